// Round 3
// baseline (523.808 us; speedup 1.0000x reference)
//
#include <hip/hip_runtime.h>
#include <math.h>

#define N_NODES 50000
#define N_EDGES 1600000
#define D 128
#define BN_EPS 1e-5f

#define NSLICE 8
#define SLICE_NODES 6250        // divides 50000 exactly; src-bucket granularity for gather L2 locality
#define SUBB 24                 // slots per (node, src-slice); Poisson(4), P(>=24)~8e-12
#define ROWL (NSLICE * SUBB)    // 192 u16 per node = 384 B
#define NREP 64                 // BN partial-sum replicas
// R13: single-pass fill (no dst-slicing). 782 gemm0 + 1264 fill = 2046 blocks
// <= 2048 residency cap (8 blocks/CU) -> zero dispatch stagger.
#define FILL_BLOCKS 1264
#define GEMM0_BLOCKS ((N_NODES + 63) / 64)   // 782 (64 rows, 4 waves) — fused with fill
#define GEMM_BLOCKS ((N_NODES + 31) / 32)    // 1563 (32 rows, 2 waves) — better tail balance

typedef __attribute__((ext_vector_type(8))) short short8;
typedef __attribute__((ext_vector_type(8))) unsigned short ushort8v;
typedef __attribute__((ext_vector_type(4))) float f32x4;

// bf16 helpers (manual, RNE)
__device__ __forceinline__ unsigned short f2bf(float f) {
    unsigned u = __float_as_uint(f);
    u += 0x7FFFu + ((u >> 16) & 1u);
    return (unsigned short)(u >> 16);
}
__device__ __forceinline__ float bf2f(unsigned short u) {
    return __uint_as_float(((unsigned)u) << 16);
}

// ============================================================
// Fill: sub-bucketed u16 CSR, ONE pass over edges, no slice filter.
// R13 rationale: the old 8-slice-team fill read dst 8x (~51MB) + src lines
// ~8x to filter 7/8 of edges away, chasing an L2 write-merge benefit that
// WRITE_SIZE=115MB (= 1.6M x 64B, zero merging) proved nonexistent. Now
// every edge is loaded exactly once; 4-way batch keeps 8 loads + 4 atomics
// in flight per iteration. csr LAYOUT is unchanged (gather unaffected).
// ============================================================
__device__ __forceinline__ void fill_one(int e, const int* __restrict__ src,
                                         const int* __restrict__ dst,
                                         unsigned int* __restrict__ cnt8,
                                         unsigned short* __restrict__ csr) {
    int d = dst[e];
    int s = src[e];
    int t = s / SLICE_NODES;
    unsigned pos = atomicAdd(&cnt8[(d << 3) + t], 1u);
    if (pos < SUBB) csr[(size_t)d * ROWL + t * SUBB + pos] = (unsigned short)s;
}

__device__ __forceinline__ void fill_body(int blk, const int* __restrict__ src,
                                          const int* __restrict__ dst,
                                          unsigned int* __restrict__ cnt8,
                                          unsigned short* __restrict__ csr) {
    const int stride = FILL_BLOCKS * 256;      // 323584; ~4.9 edges/thread
    int e = (blk - GEMM0_BLOCKS) * 256 + threadIdx.x;
    for (; e + 3 * stride < N_EDGES; e += 4 * stride) {
        int d0 = dst[e];              int s0 = src[e];
        int d1 = dst[e + stride];     int s1 = src[e + stride];
        int d2 = dst[e + 2 * stride]; int s2 = src[e + 2 * stride];
        int d3 = dst[e + 3 * stride]; int s3 = src[e + 3 * stride];
        int t0 = s0 / SLICE_NODES, t1 = s1 / SLICE_NODES;
        int t2 = s2 / SLICE_NODES, t3 = s3 / SLICE_NODES;
        unsigned p0 = atomicAdd(&cnt8[(d0 << 3) + t0], 1u);
        unsigned p1 = atomicAdd(&cnt8[(d1 << 3) + t1], 1u);
        unsigned p2 = atomicAdd(&cnt8[(d2 << 3) + t2], 1u);
        unsigned p3 = atomicAdd(&cnt8[(d3 << 3) + t3], 1u);
        if (p0 < SUBB) csr[(size_t)d0 * ROWL + t0 * SUBB + p0] = (unsigned short)s0;
        if (p1 < SUBB) csr[(size_t)d1 * ROWL + t1 * SUBB + p1] = (unsigned short)s1;
        if (p2 < SUBB) csr[(size_t)d2 * ROWL + t2 * SUBB + p2] = (unsigned short)s2;
        if (p3 < SUBB) csr[(size_t)d3 * ROWL + t3 * SUBB + p3] = (unsigned short)s3;
    }
    for (; e < N_EDGES; e += stride)
        fill_one(e, src, dst, cnt8, csr);
}

// ============================================================
// GEMM body (16 rows per wave): out[rowbase..rowbase+15] = act(A) @ W
//   apply_bn=0: A = Af32 (fp32 -> bf16), act = identity
//   apply_bn=1: A = Abf (bf16), act = relu(a*sc+sh)
// Global-direct fragments (m89-verified layouts); optional dinv row-scale.
// ============================================================
__device__ __forceinline__ void gemm_body(int rowbase, const float* __restrict__ Af32,
                                          const unsigned short* __restrict__ Abf,
                                          const unsigned short* __restrict__ Wt,
                                          const float* __restrict__ sc_sh,
                                          const float* __restrict__ dinv,
                                          int apply_bn,
                                          unsigned short* __restrict__ outbf,
                                          unsigned short* Cs) {   // per-wave 16x136 at Cs[w*2176]
    int tid = threadIdx.x;
    int w = tid >> 6;
    int lane = tid & 63;
    int r = lane & 15, quad = lane >> 4;
    rowbase += w * 16;
    int arow = rowbase + r;
    int arowc = (arow < N_NODES) ? arow : 0;

    f32x4 acc[8] = {};
#pragma unroll
    for (int kc = 0; kc < 128; kc += 32) {
        int ko = kc + quad * 8;
        short8 a;
        if (apply_bn) {
            short8 araw = *(const short8*)&Abf[(size_t)arowc * D + ko];
            const float* sc = &sc_sh[ko];
            const float* sh = &sc_sh[128 + ko];
#pragma unroll
            for (int j = 0; j < 8; j++) {
                float v = bf2f((unsigned short)araw[j]);
                v = fmaxf(fmaf(v, sc[j], sh[j]), 0.f);
                a[j] = (short)f2bf(v);
            }
        } else {
            float4 v0 = *(const float4*)&Af32[(size_t)arowc * D + ko];
            float4 v1 = *(const float4*)&Af32[(size_t)arowc * D + ko + 4];
            a[0] = (short)f2bf(v0.x); a[1] = (short)f2bf(v0.y);
            a[2] = (short)f2bf(v0.z); a[3] = (short)f2bf(v0.w);
            a[4] = (short)f2bf(v1.x); a[5] = (short)f2bf(v1.y);
            a[6] = (short)f2bf(v1.z); a[7] = (short)f2bf(v1.w);
        }
#pragma unroll
        for (int ct = 0; ct < 8; ct++) {
            short8 b = *(const short8*)&Wt[(size_t)(ct * 16 + r) * D + ko];
            acc[ct] = __builtin_amdgcn_mfma_f32_16x16x32_bf16(a, b, acc[ct], 0, 0, 0);
        }
    }
    float dv[4] = {1.f, 1.f, 1.f, 1.f};
    if (dinv) {
        float4 d4 = *(const float4*)&dinv[rowbase + quad * 4];  // padded past N
        dv[0] = d4.x; dv[1] = d4.y; dv[2] = d4.z; dv[3] = d4.w;
    }
    // epilogue: wave-private LDS staging (no cross-wave deps -> no barrier)
#pragma unroll
    for (int ct = 0; ct < 8; ct++)
#pragma unroll
        for (int i = 0; i < 4; i++)
            Cs[w * 2176 + (quad * 4 + i) * 136 + ct * 16 + r] = f2bf(acc[ct][i] * dv[i]);

    int r2 = lane >> 2;   // 0..15
    int seg = lane & 3;   // 0..3, 32 cols each
    int orow = rowbase + r2;
    if (orow < N_NODES) {
#pragma unroll
        for (int jj = 0; jj < 4; jj++) {
            *(ushort8v*)&outbf[(size_t)orow * D + seg * 32 + jj * 8] =
                *(const ushort8v*)&Cs[w * 2176 + r2 * 136 + seg * 32 + jj * 8];
        }
    }
}

// ============================================================
// Fused: layer-0 GEMM (blocks [0, 782)) || CSR fill (blocks [782, 2046)).
// All 2046 blocks co-resident at t=0 (8 blocks/CU cap) -> true overlap.
// ============================================================
__global__ __launch_bounds__(256) void fused_fill_gemm0_kernel(const int* __restrict__ src,
                                                               const int* __restrict__ dst,
                                                               unsigned int* __restrict__ cnt8,
                                                               unsigned short* __restrict__ csr,
                                                               const float* __restrict__ x,
                                                               const unsigned short* __restrict__ Wt0,
                                                               unsigned short* __restrict__ hwB) {
    __shared__ unsigned short Cs[4 * 2176];
    if (blockIdx.x < GEMM0_BLOCKS) {
        gemm_body(blockIdx.x * 64, x, nullptr, Wt0, nullptr, nullptr, 0, hwB, Cs);
    } else {
        fill_body(blockIdx.x, src, dst, cnt8, csr);
    }
}

// standalone GEMM for layers 1,2 (BN fused, dinv pre-scale); 128 thr = 2 waves,
// 32 rows/block -> 1563 blocks (782-block config wasted a 14/256 dispatch tail)
__global__ __launch_bounds__(128) void gemm_mfma_kernel(const unsigned short* __restrict__ Abf,
                                                        const unsigned short* __restrict__ Wt,
                                                        const float* __restrict__ sc_sh,
                                                        const float* __restrict__ dinv,
                                                        unsigned short* __restrict__ outbf) {
    __shared__ unsigned short Cs[2 * 2176];
    gemm_body(blockIdx.x * 32, nullptr, Abf, Wt, sc_sh, dinv, 1, outbf, Cs);
}

__global__ void compute_dinv_kernel(const unsigned int* __restrict__ cnt8, float* __restrict__ dinv) {
    int n = blockIdx.x * blockDim.x + threadIdx.x;
    if (n < N_NODES) {
        const uint4* c = (const uint4*)&cnt8[n << 3];
        uint4 a = c[0], b = c[1];
        unsigned deg = a.x + a.y + a.z + a.w + b.x + b.y + b.z + b.w;
        dinv[n] = rsqrtf((float)deg + 2.0f);   // improved=True: self-loop weight 2
    }
}

// ============================================================
// Per-layer weight prep: Wt[n][k] = bf16(W[k][n]), 3 layers, 3 blocks.
// ============================================================
__global__ void prep_weights_kernel(const float* __restrict__ W0, const float* __restrict__ W1,
                                    const float* __restrict__ W2, unsigned short* __restrict__ Wt) {
    const float* W = (blockIdx.x == 0) ? W0 : (blockIdx.x == 1) ? W1 : W2;
    unsigned short* o = Wt + (size_t)blockIdx.x * D * D;
    int t = threadIdx.x;
    int n = t & 127, half = t >> 7;
    __attribute__((aligned(16))) unsigned short buf[64];
    for (int j = 0; j < 64; j++) {
        int k = half * 64 + j;
        buf[j] = f2bf(W[(size_t)k * D + n]);
    }
    for (int j = 0; j < 64; j += 8)
        *(ushort8v*)&o[(size_t)n * D + half * 64 + j] = *(const ushort8v*)&buf[j];
}

// ============================================================
// Fused gather + BN-stats — 4 nodes/wave in 16-lane groups, lane owns
// 8 cols (ushort8 = 16B): 4 independent load chains/wave at ~30 VGPR
// (r10: 92 -> ~65us). DO NOT re-batch manually (r7/r8 regressions).
//   weighted=1 (layer 0, hw raw):   agg = di*( sum dinv[s]*hw[s] + 2*di*hw[g] )
//   weighted=0 (layers 1+, pre-scaled): agg = di*( sum hw'[s] + 2*hw'[g] )
// ============================================================
__global__ __launch_bounds__(256) void gather_agg_stats_kernel(const unsigned short* __restrict__ hw,
                                                               const unsigned short* __restrict__ csr,
                                                               const unsigned int* __restrict__ cnt8,
                                                               const float* __restrict__ dinv,
                                                               unsigned short* __restrict__ out,
                                                               float* __restrict__ rep,
                                                               int weighted) {
    __shared__ float part[16][256];
    int g16 = threadIdx.x >> 4, lane = threadIdx.x & 15;
    int g = blockIdx.x * 16 + g16;             // 3125 * 16 = 50000 exact
    const ushort8v* hwv = (const ushort8v*)hw; // row = 16 x ushort8
    float di = dinv[g];
    ushort8v sv = hwv[(size_t)g * 16 + lane];
    float w0 = weighted ? (2.f * di) : 2.f;
    float acc[8];
#pragma unroll
    for (int k = 0; k < 8; k++) acc[k] = w0 * bf2f((unsigned short)sv[k]);
    const unsigned short* row = csr + (size_t)g * ROWL;
#pragma unroll 1
    for (int t = 0; t < NSLICE; t++) {
        int dt = (int)cnt8[(g << 3) + t];
        if (dt > SUBB) dt = SUBB;
        int sA = 0, sB = 0; float wA = 0.f, wB = 0.f;
        if (lane < dt) {
            sA = (int)row[t * SUBB + lane];
            if (weighted) wA = dinv[sA];
        }
        if (lane + 16 < dt) {
            sB = (int)row[t * SUBB + 16 + lane];
            if (weighted) wB = dinv[sB];
        }
        int d1 = dt < 16 ? dt : 16;
        if (weighted) {
            for (int j = 0; j < d1; j++) {
                int sj = __shfl(sA, j, 16);
                float wj = __shfl(wA, j, 16);
                ushort8v v = hwv[(size_t)sj * 16 + lane];
#pragma unroll
                for (int k = 0; k < 8; k++) acc[k] = fmaf(wj, bf2f((unsigned short)v[k]), acc[k]);
            }
            for (int j = 0; j < dt - 16; j++) {
                int sj = __shfl(sB, j, 16);
                float wj = __shfl(wB, j, 16);
                ushort8v v = hwv[(size_t)sj * 16 + lane];
#pragma unroll
                for (int k = 0; k < 8; k++) acc[k] = fmaf(wj, bf2f((unsigned short)v[k]), acc[k]);
            }
        } else {
            for (int j = 0; j < d1; j++) {
                int sj = __shfl(sA, j, 16);
                ushort8v v = hwv[(size_t)sj * 16 + lane];
#pragma unroll
                for (int k = 0; k < 8; k++) acc[k] += bf2f((unsigned short)v[k]);
            }
            for (int j = 0; j < dt - 16; j++) {
                int sj = __shfl(sB, j, 16);
                ushort8v v = hwv[(size_t)sj * 16 + lane];
#pragma unroll
                for (int k = 0; k < 8; k++) acc[k] += bf2f((unsigned short)v[k]);
            }
        }
    }
    ushort8v o;
#pragma unroll
    for (int k = 0; k < 8; k++) { acc[k] *= di; o[k] = f2bf(acc[k]); }
    ((ushort8v*)out)[(size_t)g * 16 + lane] = o;

    // BN partials: cols c = lane*8+k; sums at [g16][c], sumsq at [g16][128+c]
    float4 s0 = make_float4(acc[0], acc[1], acc[2], acc[3]);
    float4 s1 = make_float4(acc[4], acc[5], acc[6], acc[7]);
    *(float4*)&part[g16][lane * 8]     = s0;
    *(float4*)&part[g16][lane * 8 + 4] = s1;
    *(float4*)&part[g16][128 + lane * 8] =
        make_float4(s0.x * s0.x, s0.y * s0.y, s0.z * s0.z, s0.w * s0.w);
    *(float4*)&part[g16][128 + lane * 8 + 4] =
        make_float4(s1.x * s1.x, s1.y * s1.y, s1.z * s1.z, s1.w * s1.w);
    __syncthreads();
    int c = threadIdx.x;   // 0..255: 0..127 sums, 128..255 sumsq
    float tot = 0.f;
#pragma unroll
    for (int g2 = 0; g2 < 16; g2++) tot += part[g2][c];
    atomicAdd(&rep[(blockIdx.x & (NREP - 1)) * 256 + c], tot);
}

// ============================================================
// Reduce NREP replicas -> sc/sh; re-zero replicas for next layer.
// ============================================================
__global__ void bn_reduce_finalize_kernel(const float* __restrict__ gamma,
                                          const float* __restrict__ beta,
                                          float* __restrict__ rep,
                                          float* __restrict__ sc_sh) {
    int c = threadIdx.x;
    if (c >= 128) return;
    float s = 0.f, q = 0.f;
#pragma unroll 4
    for (int rr = 0; rr < NREP; rr++) {
        s += rep[rr * 256 + c];
        q += rep[rr * 256 + 128 + c];
        rep[rr * 256 + c] = 0.f;
        rep[rr * 256 + 128 + c] = 0.f;
    }
    float inv_n = 1.0f / (float)N_NODES;
    float mean = s * inv_n;
    float var = q * inv_n - mean * mean;
    float inv = rsqrtf(var + BN_EPS);
    float sc = gamma[c] * inv;
    sc_sh[c] = sc;
    sc_sh[128 + c] = beta[c] - mean * sc;
}

// final layer: bf16 agg -> BN+ReLU -> fp32 d_out
__global__ void bn_apply_kernel(const unsigned short* __restrict__ h,
                                const float* __restrict__ sc_sh,
                                float* __restrict__ out) {
    int i = blockIdx.x * blockDim.x + threadIdx.x;
    int stride = gridDim.x * blockDim.x;
    const int total = N_NODES * 32;
    for (; i < total; i += stride) {
        int cg = i & 31;
        ushort4 u = ((const ushort4*)h)[i];
        float4 sc = ((const float4*)sc_sh)[cg];
        float4 sh = ((const float4*)sc_sh)[32 + cg];
        float4 v;
        v.x = fmaxf(fmaf(bf2f(u.x), sc.x, sh.x), 0.f);
        v.y = fmaxf(fmaf(bf2f(u.y), sc.y, sh.y), 0.f);
        v.z = fmaxf(fmaf(bf2f(u.z), sc.z, sh.z), 0.f);
        v.w = fmaxf(fmaf(bf2f(u.w), sc.w, sh.w), 0.f);
        ((float4*)out)[i] = v;
    }
}

// ============================================================
// Launch
// ============================================================
extern "C" void kernel_launch(void* const* d_in, const int* in_sizes, int n_in,
                              void* d_out, int out_size, void* d_ws, size_t ws_size,
                              hipStream_t stream) {
    const float* x = (const float*)d_in[0];
    const int* ei = (const int*)d_in[1];
    const int* src = ei;
    const int* dst = ei + N_EDGES;
    const float* Wm[3] = {(const float*)d_in[2], (const float*)d_in[6], (const float*)d_in[10]};
    const float* gm[3] = {(const float*)d_in[4], (const float*)d_in[8], (const float*)d_in[12]};
    const float* bm[3] = {(const float*)d_in[5], (const float*)d_in[9], (const float*)d_in[13]};

    char* p = (char*)d_ws;
    auto carve = [&](size_t bytes) { char* r = p; p += (bytes + 255) & ~(size_t)255; return r; };
    unsigned short* hwB    = (unsigned short*)carve((size_t)N_NODES * D * sizeof(unsigned short));
    unsigned short* aggbf  = (unsigned short*)carve((size_t)N_NODES * D * sizeof(unsigned short));
    unsigned short* Wt     = (unsigned short*)carve((size_t)3 * D * D * sizeof(unsigned short));
    float*          dinv   = (float*)carve((N_NODES + 64) * sizeof(float));
    unsigned int*   cnt8   = (unsigned int*)carve((size_t)(N_NODES * 8 + NREP * 256) * sizeof(unsigned int));
    float*          rep    = (float*)(cnt8 + (size_t)N_NODES * 8);
    unsigned short* csr    = (unsigned short*)carve((size_t)N_NODES * ROWL * sizeof(unsigned short));
    float*          sc_sh  = (float*)carve(256 * sizeof(float));

    // ---- prep: zero counters+BN replicas, transpose weights ----
    hipMemsetAsync(cnt8, 0, (size_t)(N_NODES * 8 + NREP * 256) * sizeof(unsigned int), stream);
    prep_weights_kernel<<<3, 256, 0, stream>>>(Wm[0], Wm[1], Wm[2], Wt);

    // ---- fused: layer-0 GEMM || single-pass CSR fill, all co-resident ----
    fused_fill_gemm0_kernel<<<GEMM0_BLOCKS + FILL_BLOCKS, 256, 0, stream>>>(
        src, dst, cnt8, csr, x, Wt, hwB);
    compute_dinv_kernel<<<(N_NODES + 255) / 256, 256, 0, stream>>>(cnt8, dinv);

    // ---- layer 0: weighted gather (hw unscaled) ----
    gather_agg_stats_kernel<<<N_NODES / 16, 256, 0, stream>>>(hwB, csr, cnt8, dinv, aggbf, rep, 1);
    bn_reduce_finalize_kernel<<<1, 128, 0, stream>>>(gm[0], bm[0], rep, sc_sh);

    // ---- layers 1,2: BN fused into GEMM, dinv pre-scaled hw ----
    for (int l = 1; l < 3; l++) {
        gemm_mfma_kernel<<<GEMM_BLOCKS, 128, 0, stream>>>(aggbf, Wt + (size_t)l * D * D, sc_sh, dinv, hwB);
        gather_agg_stats_kernel<<<N_NODES / 16, 256, 0, stream>>>(hwB, csr, cnt8, dinv, aggbf, rep, 0);
        bn_reduce_finalize_kernel<<<1, 128, 0, stream>>>(gm[l], bm[l], rep, sc_sh);
    }
    bn_apply_kernel<<<2048, 256, 0, stream>>>(aggbf, sc_sh, (float*)d_out);
}

// Round 5
// 515.703 us; speedup vs baseline: 1.0157x; 1.0157x over previous
//
#include <hip/hip_runtime.h>
#include <math.h>

#define N_NODES 50000
#define N_EDGES 1600000
#define D 128
#define BN_EPS 1e-5f

#define NSLICE 8
#define SLICE_NODES 6250        // divides 50000 exactly
#define SUBB 24                 // slots per (node, src-slice); Poisson(4), P(>=24)~8e-12
#define ROWL (NSLICE * SUBB)    // 192 u16 per node = 384 B
#define NREP 64                 // BN partial-sum replicas
// R14/R15 two-phase fill: phase A bins edges into per-dst-slice u32 lists
// (coalesced, single pass); phase B scatters with slice<->XCD-local atomics.
// R2 vs R3 isolated the mechanism: slicing's win is ATOMIC locality (cross-XCD
// line ping-pong costs ~30us), not write merging; the 8x scan was pure waste.
#define LIST_CAP 204800         // 200K mean +11 sigma (sigma ~418)
#define BIN_TILE 2048
#define BIN_CAP 512             // per-bucket LDS cap; mean 256, 512 = +17 sigma
#define BIN_BLOCKS ((N_EDGES + BIN_TILE - 1) / BIN_TILE)   // 782
#define FILL_BLOCKS 1264        // 8 slices x 158 teams; 782+1264 = 2046 <= 2048 resident
#define GEMM0_BLOCKS ((N_NODES + 63) / 64)   // 782 (64 rows, 4 waves) — fused with fill
#define GEMM_BLOCKS ((N_NODES + 31) / 32)    // 1563 (32 rows, 2 waves) — better tail balance

typedef __attribute__((ext_vector_type(8))) short short8;
typedef __attribute__((ext_vector_type(8))) unsigned short ushort8v;
typedef __attribute__((ext_vector_type(4))) float f32x4;

// bf16 helpers (manual, RNE)
__device__ __forceinline__ unsigned short f2bf(float f) {
    unsigned u = __float_as_uint(f);
    u += 0x7FFFu + ((u >> 16) & 1u);
    return (unsigned short)(u >> 16);
}
__device__ __forceinline__ float bf2f(unsigned short u) {
    return __uint_as_float(((unsigned)u) << 16);
}

// ============================================================
// Phase A: bin edges by dst-slice into compact u32 lists.
// Pack: val = (d << 16) | s   (both < 65536). LDS-bucket per 2048-edge
// tile, then bulk-append per bucket (1 global atomic + coalesced stores).
// ============================================================
__global__ __launch_bounds__(256) void edge_bin_kernel(const int* __restrict__ src,
                                                       const int* __restrict__ dst,
                                                       unsigned int* __restrict__ gcnt,
                                                       unsigned int* __restrict__ glist) {
    __shared__ unsigned int lcnt[NSLICE];
    __shared__ unsigned int lbase[NSLICE];
    __shared__ unsigned int lbuf[NSLICE * BIN_CAP];
    int tid = threadIdx.x;
    if (tid < NSLICE) lcnt[tid] = 0;
    __syncthreads();
    int e0 = blockIdx.x * BIN_TILE;
#pragma unroll
    for (int j = 0; j < BIN_TILE / 256; j++) {
        int e = e0 + j * 256 + tid;
        if (e < N_EDGES) {
            int d = dst[e];
            int s = src[e];
            int sl = d / SLICE_NODES;
            unsigned val = ((unsigned)d << 16) | (unsigned)s;
            unsigned pos = atomicAdd(&lcnt[sl], 1u);
            if (pos < BIN_CAP) {
                lbuf[sl * BIN_CAP + pos] = val;
            } else {  // astronomically rare overflow: correct direct append (bounds-clamped)
                unsigned gp = atomicAdd(&gcnt[sl], 1u);
                if (gp < LIST_CAP) glist[(size_t)sl * LIST_CAP + gp] = val;
            }
        }
    }
    __syncthreads();
    if (tid < NSLICE) {
        unsigned c = lcnt[tid];
        if (c > BIN_CAP) c = BIN_CAP;
        lcnt[tid] = c;
        lbase[tid] = atomicAdd(&gcnt[tid], c);
    }
    __syncthreads();
    for (int sl = 0; sl < NSLICE; sl++) {
        unsigned c = lcnt[sl], b = lbase[sl];
        for (unsigned j = tid; j < c; j += 256) {
            unsigned idx = b + j;
            if (idx < LIST_CAP) glist[(size_t)sl * LIST_CAP + idx] = lbuf[sl * BIN_CAP + j];
        }
    }
}

// ============================================================
// Phase B: XCD-local scatter. slice = blk & 7 keeps slice<->XCD binding
// (round-robin block->XCD): each team's cnt8/csr region is touched by ONE
// XCD only -> atomics RMW in the local L2 instead of cross-XCD ping-pong.
// Reads: only this slice's 800KB compact list (vs 8x full-edge scan in R2).
// ============================================================
__device__ __forceinline__ void fill_scatter(unsigned v,
                                             unsigned int* __restrict__ cnt8,
                                             unsigned short* __restrict__ csr) {
    int d = (int)(v >> 16);
    int s = (int)(v & 0xFFFFu);
    int t = s / SLICE_NODES;
    unsigned pos = atomicAdd(&cnt8[(d << 3) + t], 1u);
    if (pos < SUBB) csr[(size_t)d * ROWL + t * SUBB + pos] = (unsigned short)s;
}

__device__ __forceinline__ void fill_body(int blk,
                                          const unsigned int* __restrict__ glist,
                                          const unsigned int* __restrict__ gcnt,
                                          unsigned int* __restrict__ cnt8,
                                          unsigned short* __restrict__ csr) {
    int slice = blk & (NSLICE - 1);
    int trank = (blk - GEMM0_BLOCKS) >> 3;             // 0..157
    const unsigned int* list = glist + (size_t)slice * LIST_CAP;
    int L = (int)gcnt[slice];                          // ~200K
    if (L > LIST_CAP) L = LIST_CAP;                    // defensive clamp
    const int stride = (FILL_BLOCKS >> 3) * 256;       // 40448
    int k = trank * 256 + threadIdx.x;
    for (; k + 3 * stride < L; k += 4 * stride) {      // 4 chains in flight
        unsigned v0 = list[k];
        unsigned v1 = list[k + stride];
        unsigned v2 = list[k + 2 * stride];
        unsigned v3 = list[k + 3 * stride];
        fill_scatter(v0, cnt8, csr);
        fill_scatter(v1, cnt8, csr);
        fill_scatter(v2, cnt8, csr);
        fill_scatter(v3, cnt8, csr);
    }
    for (; k < L; k += stride)
        fill_scatter(list[k], cnt8, csr);
}

// ============================================================
// GEMM body (16 rows per wave): out[rowbase..rowbase+15] = act(A) @ W
//   apply_bn=0: A = Af32 (fp32 -> bf16), act = identity
//   apply_bn=1: A = Abf (bf16), act = relu(a*sc+sh)
// Global-direct fragments (m89-verified layouts); optional dinv row-scale.
// ============================================================
__device__ __forceinline__ void gemm_body(int rowbase, const float* __restrict__ Af32,
                                          const unsigned short* __restrict__ Abf,
                                          const unsigned short* __restrict__ Wt,
                                          const float* __restrict__ sc_sh,
                                          const float* __restrict__ dinv,
                                          int apply_bn,
                                          unsigned short* __restrict__ outbf,
                                          unsigned short* Cs) {   // per-wave 16x136 at Cs[w*2176]
    int tid = threadIdx.x;
    int w = tid >> 6;
    int lane = tid & 63;
    int r = lane & 15, quad = lane >> 4;
    rowbase += w * 16;
    int arow = rowbase + r;
    int arowc = (arow < N_NODES) ? arow : 0;

    f32x4 acc[8] = {};
#pragma unroll
    for (int kc = 0; kc < 128; kc += 32) {
        int ko = kc + quad * 8;
        short8 a;
        if (apply_bn) {
            short8 araw = *(const short8*)&Abf[(size_t)arowc * D + ko];
            const float* sc = &sc_sh[ko];
            const float* sh = &sc_sh[128 + ko];
#pragma unroll
            for (int j = 0; j < 8; j++) {
                float v = bf2f((unsigned short)araw[j]);
                v = fmaxf(fmaf(v, sc[j], sh[j]), 0.f);
                a[j] = (short)f2bf(v);
            }
        } else {
            float4 v0 = *(const float4*)&Af32[(size_t)arowc * D + ko];
            float4 v1 = *(const float4*)&Af32[(size_t)arowc * D + ko + 4];
            a[0] = (short)f2bf(v0.x); a[1] = (short)f2bf(v0.y);
            a[2] = (short)f2bf(v0.z); a[3] = (short)f2bf(v0.w);
            a[4] = (short)f2bf(v1.x); a[5] = (short)f2bf(v1.y);
            a[6] = (short)f2bf(v1.z); a[7] = (short)f2bf(v1.w);
        }
#pragma unroll
        for (int ct = 0; ct < 8; ct++) {
            short8 b = *(const short8*)&Wt[(size_t)(ct * 16 + r) * D + ko];
            acc[ct] = __builtin_amdgcn_mfma_f32_16x16x32_bf16(a, b, acc[ct], 0, 0, 0);
        }
    }
    float dv[4] = {1.f, 1.f, 1.f, 1.f};
    if (dinv) {
        float4 d4 = *(const float4*)&dinv[rowbase + quad * 4];  // padded past N
        dv[0] = d4.x; dv[1] = d4.y; dv[2] = d4.z; dv[3] = d4.w;
    }
    // epilogue: wave-private LDS staging (no cross-wave deps -> no barrier)
#pragma unroll
    for (int ct = 0; ct < 8; ct++)
#pragma unroll
        for (int i = 0; i < 4; i++)
            Cs[w * 2176 + (quad * 4 + i) * 136 + ct * 16 + r] = f2bf(acc[ct][i] * dv[i]);

    int r2 = lane >> 2;   // 0..15
    int seg = lane & 3;   // 0..3, 32 cols each
    int orow = rowbase + r2;
    if (orow < N_NODES) {
#pragma unroll
        for (int jj = 0; jj < 4; jj++) {
            *(ushort8v*)&outbf[(size_t)orow * D + seg * 32 + jj * 8] =
                *(const ushort8v*)&Cs[w * 2176 + r2 * 136 + seg * 32 + jj * 8];
        }
    }
}

// ============================================================
// Fused: layer-0 GEMM (blocks [0, 782)) || phase-B scatter ([782, 2046)).
// All 2046 blocks co-resident at t=0 (8 blocks/CU cap) -> true overlap.
// ============================================================
__global__ __launch_bounds__(256) void fused_fill_gemm0_kernel(const unsigned int* __restrict__ glist,
                                                               const unsigned int* __restrict__ gcnt,
                                                               unsigned int* __restrict__ cnt8,
                                                               unsigned short* __restrict__ csr,
                                                               const float* __restrict__ x,
                                                               const unsigned short* __restrict__ Wt0,
                                                               unsigned short* __restrict__ hwB) {
    __shared__ unsigned short Cs[4 * 2176];
    if (blockIdx.x < GEMM0_BLOCKS) {
        gemm_body(blockIdx.x * 64, x, nullptr, Wt0, nullptr, nullptr, 0, hwB, Cs);
    } else {
        fill_body(blockIdx.x, glist, gcnt, cnt8, csr);
    }
}

// standalone GEMM for layers 1,2 (BN fused, dinv pre-scale); 128 thr = 2 waves,
// 32 rows/block -> 1563 blocks (782-block config wasted a 14/256 dispatch tail)
__global__ __launch_bounds__(128) void gemm_mfma_kernel(const unsigned short* __restrict__ Abf,
                                                        const unsigned short* __restrict__ Wt,
                                                        const float* __restrict__ sc_sh,
                                                        const float* __restrict__ dinv,
                                                        unsigned short* __restrict__ outbf) {
    __shared__ unsigned short Cs[2 * 2176];
    gemm_body(blockIdx.x * 32, nullptr, Abf, Wt, sc_sh, dinv, 1, outbf, Cs);
}

__global__ void compute_dinv_kernel(const unsigned int* __restrict__ cnt8, float* __restrict__ dinv) {
    int n = blockIdx.x * blockDim.x + threadIdx.x;
    if (n < N_NODES) {
        const uint4* c = (const uint4*)&cnt8[n << 3];
        uint4 a = c[0], b = c[1];
        unsigned deg = a.x + a.y + a.z + a.w + b.x + b.y + b.z + b.w;
        dinv[n] = rsqrtf((float)deg + 2.0f);   // improved=True: self-loop weight 2
    }
}

// ============================================================
// Per-layer weight prep: Wt[n][k] = bf16(W[k][n]), 3 layers, 3 blocks.
// ============================================================
__global__ void prep_weights_kernel(const float* __restrict__ W0, const float* __restrict__ W1,
                                    const float* __restrict__ W2, unsigned short* __restrict__ Wt) {
    const float* W = (blockIdx.x == 0) ? W0 : (blockIdx.x == 1) ? W1 : W2;
    unsigned short* o = Wt + (size_t)blockIdx.x * D * D;
    int t = threadIdx.x;
    int n = t & 127, half = t >> 7;
    __attribute__((aligned(16))) unsigned short buf[64];
    for (int j = 0; j < 64; j++) {
        int k = half * 64 + j;
        buf[j] = f2bf(W[(size_t)k * D + n]);
    }
    for (int j = 0; j < 64; j += 8)
        *(ushort8v*)&o[(size_t)n * D + half * 64 + j] = *(const ushort8v*)&buf[j];
}

// ============================================================
// Fused gather + BN-stats — 4 nodes/wave in 16-lane groups, lane owns
// 8 cols (ushort8 = 16B): 4 independent load chains/wave at ~30 VGPR
// (r10: 92 -> ~65us). DO NOT re-batch manually (r7/r8 regressions).
//   weighted=1 (layer 0, hw raw):   agg = di*( sum dinv[s]*hw[s] + 2*di*hw[g] )
//   weighted=0 (layers 1+, pre-scaled): agg = di*( sum hw'[s] + 2*hw'[g] )
// ============================================================
__global__ __launch_bounds__(256) void gather_agg_stats_kernel(const unsigned short* __restrict__ hw,
                                                               const unsigned short* __restrict__ csr,
                                                               const unsigned int* __restrict__ cnt8,
                                                               const float* __restrict__ dinv,
                                                               unsigned short* __restrict__ out,
                                                               float* __restrict__ rep,
                                                               int weighted) {
    __shared__ float part[16][256];
    int g16 = threadIdx.x >> 4, lane = threadIdx.x & 15;
    int g = blockIdx.x * 16 + g16;             // 3125 * 16 = 50000 exact
    const ushort8v* hwv = (const ushort8v*)hw; // row = 16 x ushort8
    float di = dinv[g];
    ushort8v sv = hwv[(size_t)g * 16 + lane];
    float w0 = weighted ? (2.f * di) : 2.f;
    float acc[8];
#pragma unroll
    for (int k = 0; k < 8; k++) acc[k] = w0 * bf2f((unsigned short)sv[k]);
    const unsigned short* row = csr + (size_t)g * ROWL;
#pragma unroll 1
    for (int t = 0; t < NSLICE; t++) {
        int dt = (int)cnt8[(g << 3) + t];
        if (dt > SUBB) dt = SUBB;
        int sA = 0, sB = 0; float wA = 0.f, wB = 0.f;
        if (lane < dt) {
            sA = (int)row[t * SUBB + lane];
            if (weighted) wA = dinv[sA];
        }
        if (lane + 16 < dt) {
            sB = (int)row[t * SUBB + 16 + lane];
            if (weighted) wB = dinv[sB];
        }
        int d1 = dt < 16 ? dt : 16;
        if (weighted) {
            for (int j = 0; j < d1; j++) {
                int sj = __shfl(sA, j, 16);
                float wj = __shfl(wA, j, 16);
                ushort8v v = hwv[(size_t)sj * 16 + lane];
#pragma unroll
                for (int k = 0; k < 8; k++) acc[k] = fmaf(wj, bf2f((unsigned short)v[k]), acc[k]);
            }
            for (int j = 0; j < dt - 16; j++) {
                int sj = __shfl(sB, j, 16);
                float wj = __shfl(wB, j, 16);
                ushort8v v = hwv[(size_t)sj * 16 + lane];
#pragma unroll
                for (int k = 0; k < 8; k++) acc[k] = fmaf(wj, bf2f((unsigned short)v[k]), acc[k]);
            }
        } else {
            for (int j = 0; j < d1; j++) {
                int sj = __shfl(sA, j, 16);
                ushort8v v = hwv[(size_t)sj * 16 + lane];
#pragma unroll
                for (int k = 0; k < 8; k++) acc[k] += bf2f((unsigned short)v[k]);
            }
            for (int j = 0; j < dt - 16; j++) {
                int sj = __shfl(sB, j, 16);
                ushort8v v = hwv[(size_t)sj * 16 + lane];
#pragma unroll
                for (int k = 0; k < 8; k++) acc[k] += bf2f((unsigned short)v[k]);
            }
        }
    }
    ushort8v o;
#pragma unroll
    for (int k = 0; k < 8; k++) { acc[k] *= di; o[k] = f2bf(acc[k]); }
    ((ushort8v*)out)[(size_t)g * 16 + lane] = o;

    // BN partials: cols c = lane*8+k; sums at [g16][c], sumsq at [g16][128+c]
    float4 s0 = make_float4(acc[0], acc[1], acc[2], acc[3]);
    float4 s1 = make_float4(acc[4], acc[5], acc[6], acc[7]);
    *(float4*)&part[g16][lane * 8]     = s0;
    *(float4*)&part[g16][lane * 8 + 4] = s1;
    *(float4*)&part[g16][128 + lane * 8] =
        make_float4(s0.x * s0.x, s0.y * s0.y, s0.z * s0.z, s0.w * s0.w);
    *(float4*)&part[g16][128 + lane * 8 + 4] =
        make_float4(s1.x * s1.x, s1.y * s1.y, s1.z * s1.z, s1.w * s1.w);
    __syncthreads();
    int c = threadIdx.x;   // 0..255: 0..127 sums, 128..255 sumsq
    float tot = 0.f;
#pragma unroll
    for (int g2 = 0; g2 < 16; g2++) tot += part[g2][c];
    atomicAdd(&rep[(blockIdx.x & (NREP - 1)) * 256 + c], tot);
}

// ============================================================
// Reduce NREP replicas -> sc/sh; re-zero replicas for next layer.
// ============================================================
__global__ void bn_reduce_finalize_kernel(const float* __restrict__ gamma,
                                          const float* __restrict__ beta,
                                          float* __restrict__ rep,
                                          float* __restrict__ sc_sh) {
    int c = threadIdx.x;
    if (c >= 128) return;
    float s = 0.f, q = 0.f;
#pragma unroll 4
    for (int rr = 0; rr < NREP; rr++) {
        s += rep[rr * 256 + c];
        q += rep[rr * 256 + 128 + c];
        rep[rr * 256 + c] = 0.f;
        rep[rr * 256 + 128 + c] = 0.f;
    }
    float inv_n = 1.0f / (float)N_NODES;
    float mean = s * inv_n;
    float var = q * inv_n - mean * mean;
    float inv = rsqrtf(var + BN_EPS);
    float sc = gamma[c] * inv;
    sc_sh[c] = sc;
    sc_sh[128 + c] = beta[c] - mean * sc;
}

// final layer: bf16 agg -> BN+ReLU -> fp32 d_out
__global__ void bn_apply_kernel(const unsigned short* __restrict__ h,
                                const float* __restrict__ sc_sh,
                                float* __restrict__ out) {
    int i = blockIdx.x * blockDim.x + threadIdx.x;
    int stride = gridDim.x * blockDim.x;
    const int total = N_NODES * 32;
    for (; i < total; i += stride) {
        int cg = i & 31;
        ushort4 u = ((const ushort4*)h)[i];
        float4 sc = ((const float4*)sc_sh)[cg];
        float4 sh = ((const float4*)sc_sh)[32 + cg];
        float4 v;
        v.x = fmaxf(fmaf(bf2f(u.x), sc.x, sh.x), 0.f);
        v.y = fmaxf(fmaf(bf2f(u.y), sc.y, sh.y), 0.f);
        v.z = fmaxf(fmaf(bf2f(u.z), sc.z, sh.z), 0.f);
        v.w = fmaxf(fmaf(bf2f(u.w), sc.w, sh.w), 0.f);
        ((float4*)out)[i] = v;
    }
}

// ============================================================
// Launch
// ============================================================
extern "C" void kernel_launch(void* const* d_in, const int* in_sizes, int n_in,
                              void* d_out, int out_size, void* d_ws, size_t ws_size,
                              hipStream_t stream) {
    const float* x = (const float*)d_in[0];
    const int* ei = (const int*)d_in[1];
    const int* src = ei;
    const int* dst = ei + N_EDGES;
    const float* Wm[3] = {(const float*)d_in[2], (const float*)d_in[6], (const float*)d_in[10]};
    const float* gm[3] = {(const float*)d_in[4], (const float*)d_in[8], (const float*)d_in[12]};
    const float* bm[3] = {(const float*)d_in[5], (const float*)d_in[9], (const float*)d_in[13]};

    char* p = (char*)d_ws;
    auto carve = [&](size_t bytes) { char* r = p; p += (bytes + 255) & ~(size_t)255; return r; };
    unsigned short* hwB    = (unsigned short*)carve((size_t)N_NODES * D * sizeof(unsigned short));
    unsigned short* aggbf  = (unsigned short*)carve((size_t)N_NODES * D * sizeof(unsigned short));
    unsigned short* Wt     = (unsigned short*)carve((size_t)3 * D * D * sizeof(unsigned short));
    float*          dinv   = (float*)carve((N_NODES + 64) * sizeof(float));
    // cnt8 | rep | gcnt share one zeroed region (one memset covers all three)
    unsigned int*   cnt8   = (unsigned int*)carve((size_t)(N_NODES * 8 + NREP * 256 + 8) * sizeof(unsigned int));
    float*          rep    = (float*)(cnt8 + (size_t)N_NODES * 8);
    unsigned int*   gcnt   = cnt8 + (size_t)N_NODES * 8 + NREP * 256;
    unsigned short* csr    = (unsigned short*)carve((size_t)N_NODES * ROWL * sizeof(unsigned short));
    unsigned int*   glist  = (unsigned int*)carve((size_t)NSLICE * LIST_CAP * sizeof(unsigned int));
    float*          sc_sh  = (float*)carve(256 * sizeof(float));

    // ---- prep: zero counters+BN replicas+list heads, transpose weights ----
    hipMemsetAsync(cnt8, 0, (size_t)(N_NODES * 8 + NREP * 256 + 8) * sizeof(unsigned int), stream);
    prep_weights_kernel<<<3, 256, 0, stream>>>(Wm[0], Wm[1], Wm[2], Wt);

    // ---- phase A: coalesced edge binning into per-slice lists ----
    edge_bin_kernel<<<BIN_BLOCKS, 256, 0, stream>>>(src, dst, gcnt, glist);

    // ---- fused: layer-0 GEMM || phase-B XCD-local scatter ----
    fused_fill_gemm0_kernel<<<GEMM0_BLOCKS + FILL_BLOCKS, 256, 0, stream>>>(
        glist, gcnt, cnt8, csr, x, Wt, hwB);
    compute_dinv_kernel<<<(N_NODES + 255) / 256, 256, 0, stream>>>(cnt8, dinv);

    // ---- layer 0: weighted gather (hw unscaled) ----
    gather_agg_stats_kernel<<<N_NODES / 16, 256, 0, stream>>>(hwB, csr, cnt8, dinv, aggbf, rep, 1);
    bn_reduce_finalize_kernel<<<1, 128, 0, stream>>>(gm[0], bm[0], rep, sc_sh);

    // ---- layers 1,2: BN fused into GEMM, dinv pre-scaled hw ----
    for (int l = 1; l < 3; l++) {
        gemm_mfma_kernel<<<GEMM_BLOCKS, 128, 0, stream>>>(aggbf, Wt + (size_t)l * D * D, sc_sh, dinv, hwB);
        gather_agg_stats_kernel<<<N_NODES / 16, 256, 0, stream>>>(hwB, csr, cnt8, dinv, aggbf, rep, 0);
        bn_reduce_finalize_kernel<<<1, 128, 0, stream>>>(gm[l], bm[l], rep, sc_sh);
    }
    bn_apply_kernel<<<2048, 256, 0, stream>>>(aggbf, sc_sh, (float*)d_out);
}

// Round 6
// 455.336 us; speedup vs baseline: 1.1504x; 1.1326x over previous
//
#include <hip/hip_runtime.h>
#include <math.h>

#define N_NODES 50000
#define N_EDGES 1600000
#define D 128
#define BN_EPS 1e-5f

#define NSLICE 8
#define SLICE_NODES 6250        // divides 50000 exactly; src-bucket granularity for gather L2 locality
#define SUBB 24                 // slots per (node, src-slice); Poisson(4), P(>=24)~8e-12
#define ROWL (NSLICE * SUBB)    // 192 u16 per node = 384 B
#define NREP 64                 // BN partial-sum replicas

// R16: LDS-scatter CSR build. R2/R3/R5 triangulated that the fill wall is the
// 1.6M returning L2 atomics + dependent 2B scatters themselves (~64 atomics/
// counter-line serialized; WRITE_SIZE 106MB partial-line RMW) — not reads, not
// XCD locality. Fix: counters+csr rows for a 100-node range fit in LDS, so
// phase A bins edges by dst-range (bulk-reserved appends, ~391K amortized
// atomics), phase B scatters ENTIRELY in LDS and writes csr/cnt8 coalesced.
#define NRANGE 500
#define RANGE_NODES 100         // 500 * 100 = 50000 exact
#define NSUB 8                  // sub-heads per range (blockIdx&7) to cut reserve contention
#define SEG_CAP 512             // per-(range,sub) list segment; mean 400, +5.6 sigma
#define BIN_TILE 2048
#define BIN_CAP2 16             // per-tile per-range LDS bucket; mean 4.1, P(>16)~5e-6
#define BIN_BLOCKS ((N_EDGES + BIN_TILE - 1) / BIN_TILE)  // 782
#define GEMM0_BLOCKS ((N_NODES + 63) / 64)   // 782 (64 rows, 4 waves) — fused with phase A
#define GEMM_BLOCKS ((N_NODES + 31) / 32)    // 1563 (32 rows, 2 waves)

typedef __attribute__((ext_vector_type(8))) short short8;
typedef __attribute__((ext_vector_type(8))) unsigned short ushort8v;
typedef __attribute__((ext_vector_type(4))) float f32x4;

// bf16 helpers (manual, RNE)
__device__ __forceinline__ unsigned short f2bf(float f) {
    unsigned u = __float_as_uint(f);
    u += 0x7FFFu + ((u >> 16) & 1u);
    return (unsigned short)(u >> 16);
}
__device__ __forceinline__ float bf2f(unsigned short u) {
    return __uint_as_float(((unsigned)u) << 16);
}

// ============================================================
// GEMM body (16 rows per wave): out[rowbase..rowbase+15] = act(A) @ W
//   apply_bn=0: A = Af32 (fp32 -> bf16), act = identity
//   apply_bn=1: A = Abf (bf16), act = relu(a*sc+sh)
// Global-direct fragments (m89-verified layouts); optional dinv row-scale.
// ============================================================
__device__ __forceinline__ void gemm_body(int rowbase, const float* __restrict__ Af32,
                                          const unsigned short* __restrict__ Abf,
                                          const unsigned short* __restrict__ Wt,
                                          const float* __restrict__ sc_sh,
                                          const float* __restrict__ dinv,
                                          int apply_bn,
                                          unsigned short* __restrict__ outbf,
                                          unsigned short* Cs) {   // per-wave 16x136 at Cs[w*2176]
    int tid = threadIdx.x;
    int w = tid >> 6;
    int lane = tid & 63;
    int r = lane & 15, quad = lane >> 4;
    rowbase += w * 16;
    int arow = rowbase + r;
    int arowc = (arow < N_NODES) ? arow : 0;

    f32x4 acc[8] = {};
#pragma unroll
    for (int kc = 0; kc < 128; kc += 32) {
        int ko = kc + quad * 8;
        short8 a;
        if (apply_bn) {
            short8 araw = *(const short8*)&Abf[(size_t)arowc * D + ko];
            const float* sc = &sc_sh[ko];
            const float* sh = &sc_sh[128 + ko];
#pragma unroll
            for (int j = 0; j < 8; j++) {
                float v = bf2f((unsigned short)araw[j]);
                v = fmaxf(fmaf(v, sc[j], sh[j]), 0.f);
                a[j] = (short)f2bf(v);
            }
        } else {
            float4 v0 = *(const float4*)&Af32[(size_t)arowc * D + ko];
            float4 v1 = *(const float4*)&Af32[(size_t)arowc * D + ko + 4];
            a[0] = (short)f2bf(v0.x); a[1] = (short)f2bf(v0.y);
            a[2] = (short)f2bf(v0.z); a[3] = (short)f2bf(v0.w);
            a[4] = (short)f2bf(v1.x); a[5] = (short)f2bf(v1.y);
            a[6] = (short)f2bf(v1.z); a[7] = (short)f2bf(v1.w);
        }
#pragma unroll
        for (int ct = 0; ct < 8; ct++) {
            short8 b = *(const short8*)&Wt[(size_t)(ct * 16 + r) * D + ko];
            acc[ct] = __builtin_amdgcn_mfma_f32_16x16x32_bf16(a, b, acc[ct], 0, 0, 0);
        }
    }
    float dv[4] = {1.f, 1.f, 1.f, 1.f};
    if (dinv) {
        float4 d4 = *(const float4*)&dinv[rowbase + quad * 4];  // padded past N
        dv[0] = d4.x; dv[1] = d4.y; dv[2] = d4.z; dv[3] = d4.w;
    }
    // epilogue: wave-private LDS staging (no cross-wave deps -> no barrier)
#pragma unroll
    for (int ct = 0; ct < 8; ct++)
#pragma unroll
        for (int i = 0; i < 4; i++)
            Cs[w * 2176 + (quad * 4 + i) * 136 + ct * 16 + r] = f2bf(acc[ct][i] * dv[i]);

    int r2 = lane >> 2;   // 0..15
    int seg = lane & 3;   // 0..3, 32 cols each
    int orow = rowbase + r2;
    if (orow < N_NODES) {
#pragma unroll
        for (int jj = 0; jj < 4; jj++) {
            *(ushort8v*)&outbf[(size_t)orow * D + seg * 32 + jj * 8] =
                *(const ushort8v*)&Cs[w * 2176 + r2 * 136 + seg * 32 + jj * 8];
        }
    }
}

// ============================================================
// Fused: phase-A edge binning (blocks [0,782)) || layer-0 GEMM ([782,1564)).
// Phase A: LDS-bucket 2048 edges into 500 dst-range bins, bulk-reserve into
// per-(range, blockIdx&7) global segments. ~500 amortized global atomics per
// block instead of 2048 fine-grained ones. A-first ordering: phase B depends
// on ALL of A; gemm0 can straggle.
// ============================================================
__global__ __launch_bounds__(256) void fused_bin_gemm0_kernel(const int* __restrict__ src,
                                                              const int* __restrict__ dst,
                                                              unsigned int* __restrict__ gcnt,
                                                              unsigned int* __restrict__ glist,
                                                              const float* __restrict__ x,
                                                              const unsigned short* __restrict__ Wt0,
                                                              unsigned short* __restrict__ hwB) {
    __shared__ __align__(16) char smem[34000];   // union: binning 34000B | gemm0 Cs 17408B
    if (blockIdx.x < BIN_BLOCKS) {
        unsigned* lcnt = (unsigned*)smem;                 // [500]
        unsigned* lbuf = (unsigned*)(smem + 2000);        // [500 * 16]
        int tid = threadIdx.x;
        int sub = blockIdx.x & (NSUB - 1);
        for (int i = tid; i < NRANGE; i += 256) lcnt[i] = 0;
        __syncthreads();
        int e0 = blockIdx.x * BIN_TILE;
#pragma unroll
        for (int j = 0; j < BIN_TILE / 256; j++) {
            int e = e0 + j * 256 + tid;
            if (e < N_EDGES) {
                int d = dst[e];
                int s = src[e];
                int rg = d / RANGE_NODES;
                unsigned val = ((unsigned)(d - rg * RANGE_NODES) << 16) | (unsigned)s;
                unsigned pos = atomicAdd(&lcnt[rg], 1u);
                if (pos < BIN_CAP2) {
                    lbuf[rg * BIN_CAP2 + pos] = val;
                } else {   // rare bucket overflow (~10 events/run): direct bounded append
                    unsigned gp = atomicAdd(&gcnt[rg * NSUB + sub], 1u);
                    if (gp < SEG_CAP) glist[(size_t)(rg * NSUB + sub) * SEG_CAP + gp] = val;
                }
            }
        }
        __syncthreads();
        // bulk-reserve + flush: thread t owns ranges t, t+256
        for (int rg = tid; rg < NRANGE; rg += 256) {
            unsigned c = lcnt[rg];
            if (c > BIN_CAP2) c = BIN_CAP2;
            if (c == 0) continue;
            unsigned b = atomicAdd(&gcnt[rg * NSUB + sub], c);
            unsigned base = (unsigned)(rg * NSUB + sub) * SEG_CAP;
            for (unsigned j = 0; j < c; j++) {
                unsigned idx = b + j;
                if (idx < SEG_CAP) glist[base + idx] = lbuf[rg * BIN_CAP2 + j];
            }
        }
    } else {
        gemm_body((blockIdx.x - BIN_BLOCKS) * 64, x, nullptr, Wt0, nullptr, nullptr, 0, hwB,
                  (unsigned short*)smem);
    }
}

// ============================================================
// Phase B: per-range LDS scatter. Block rg owns nodes [rg*100, rg*100+100):
// counters (800 u32) + csr slab (100x192 u16) live in LDS; the 1.6M global
// atomics of the old fill become LDS atomics (~30cyc, no coherence traffic).
// csr + cnt8 written out fully coalesced, exactly once.
// ============================================================
__global__ __launch_bounds__(256) void csr_scatter_kernel(const unsigned int* __restrict__ glist,
                                                          const unsigned int* __restrict__ gcnt,
                                                          unsigned int* __restrict__ cnt8,
                                                          unsigned short* __restrict__ csr) {
    __shared__ __align__(16) unsigned int cnt[RANGE_NODES * 8];        // 3200 B
    __shared__ __align__(16) unsigned short slab[RANGE_NODES * ROWL];  // 38400 B
    int tid = threadIdx.x;
    int rg = blockIdx.x;
    for (int i = tid; i < RANGE_NODES * 8; i += 256) cnt[i] = 0;
    __syncthreads();
#pragma unroll 1
    for (int sub = 0; sub < NSUB; sub++) {
        unsigned c = gcnt[rg * NSUB + sub];
        if (c > SEG_CAP) c = SEG_CAP;
        const unsigned int* seg = glist + (size_t)(rg * NSUB + sub) * SEG_CAP;
        for (unsigned j = tid; j < c; j += 256) {
            unsigned v = seg[j];
            int dl = (int)(v >> 16);
            int s = (int)(v & 0xFFFFu);
            int t = s / SLICE_NODES;
            unsigned pos = atomicAdd(&cnt[dl * 8 + t], 1u);   // LDS atomic
            if (pos < SUBB) slab[dl * ROWL + t * SUBB + pos] = (unsigned short)s;
        }
    }
    __syncthreads();
    // coalesced write-out: 2400 x ushort8 csr + 200 x uint4 counters
    unsigned short* crow = csr + (size_t)rg * RANGE_NODES * ROWL;
    const ushort8v* sl = (const ushort8v*)slab;
    for (int i = tid; i < RANGE_NODES * ROWL / 8; i += 256)
        ((ushort8v*)crow)[i] = sl[i];
    unsigned int* gout = cnt8 + (size_t)rg * RANGE_NODES * 8;
    const uint4* cl = (const uint4*)cnt;
    for (int i = tid; i < RANGE_NODES * 8 / 4; i += 256)
        ((uint4*)gout)[i] = cl[i];
}

// standalone GEMM for layers 1,2 (BN fused, dinv pre-scale); 128 thr = 2 waves,
// 32 rows/block -> 1563 blocks (782-block config wasted a 14/256 dispatch tail)
__global__ __launch_bounds__(128) void gemm_mfma_kernel(const unsigned short* __restrict__ Abf,
                                                        const unsigned short* __restrict__ Wt,
                                                        const float* __restrict__ sc_sh,
                                                        const float* __restrict__ dinv,
                                                        unsigned short* __restrict__ outbf) {
    __shared__ unsigned short Cs[2 * 2176];
    gemm_body(blockIdx.x * 32, nullptr, Abf, Wt, sc_sh, dinv, 1, outbf, Cs);
}

__global__ void compute_dinv_kernel(const unsigned int* __restrict__ cnt8, float* __restrict__ dinv) {
    int n = blockIdx.x * blockDim.x + threadIdx.x;
    if (n < N_NODES) {
        const uint4* c = (const uint4*)&cnt8[n << 3];
        uint4 a = c[0], b = c[1];
        unsigned deg = a.x + a.y + a.z + a.w + b.x + b.y + b.z + b.w;
        dinv[n] = rsqrtf((float)deg + 2.0f);   // improved=True: self-loop weight 2
    }
}

// ============================================================
// Per-layer weight prep: Wt[n][k] = bf16(W[k][n]), 3 layers, 3 blocks.
// ============================================================
__global__ void prep_weights_kernel(const float* __restrict__ W0, const float* __restrict__ W1,
                                    const float* __restrict__ W2, unsigned short* __restrict__ Wt) {
    const float* W = (blockIdx.x == 0) ? W0 : (blockIdx.x == 1) ? W1 : W2;
    unsigned short* o = Wt + (size_t)blockIdx.x * D * D;
    int t = threadIdx.x;
    int n = t & 127, half = t >> 7;
    __attribute__((aligned(16))) unsigned short buf[64];
    for (int j = 0; j < 64; j++) {
        int k = half * 64 + j;
        buf[j] = f2bf(W[(size_t)k * D + n]);
    }
    for (int j = 0; j < 64; j += 8)
        *(ushort8v*)&o[(size_t)n * D + half * 64 + j] = *(const ushort8v*)&buf[j];
}

// ============================================================
// Fused gather + BN-stats — 4 nodes/wave in 16-lane groups, lane owns
// 8 cols (ushort8 = 16B): 4 independent load chains/wave at ~30 VGPR
// (r10: 92 -> ~65us). DO NOT re-batch manually (r7/r8 regressions).
//   weighted=1 (layer 0, hw raw):   agg = di*( sum dinv[s]*hw[s] + 2*di*hw[g] )
//   weighted=0 (layers 1+, pre-scaled): agg = di*( sum hw'[s] + 2*hw'[g] )
// ============================================================
__global__ __launch_bounds__(256) void gather_agg_stats_kernel(const unsigned short* __restrict__ hw,
                                                               const unsigned short* __restrict__ csr,
                                                               const unsigned int* __restrict__ cnt8,
                                                               const float* __restrict__ dinv,
                                                               unsigned short* __restrict__ out,
                                                               float* __restrict__ rep,
                                                               int weighted) {
    __shared__ float part[16][256];
    int g16 = threadIdx.x >> 4, lane = threadIdx.x & 15;
    int g = blockIdx.x * 16 + g16;             // 3125 * 16 = 50000 exact
    const ushort8v* hwv = (const ushort8v*)hw; // row = 16 x ushort8
    float di = dinv[g];
    ushort8v sv = hwv[(size_t)g * 16 + lane];
    float w0 = weighted ? (2.f * di) : 2.f;
    float acc[8];
#pragma unroll
    for (int k = 0; k < 8; k++) acc[k] = w0 * bf2f((unsigned short)sv[k]);
    const unsigned short* row = csr + (size_t)g * ROWL;
#pragma unroll 1
    for (int t = 0; t < NSLICE; t++) {
        int dt = (int)cnt8[(g << 3) + t];
        if (dt > SUBB) dt = SUBB;
        int sA = 0, sB = 0; float wA = 0.f, wB = 0.f;
        if (lane < dt) {
            sA = (int)row[t * SUBB + lane];
            if (weighted) wA = dinv[sA];
        }
        if (lane + 16 < dt) {
            sB = (int)row[t * SUBB + 16 + lane];
            if (weighted) wB = dinv[sB];
        }
        int d1 = dt < 16 ? dt : 16;
        if (weighted) {
            for (int j = 0; j < d1; j++) {
                int sj = __shfl(sA, j, 16);
                float wj = __shfl(wA, j, 16);
                ushort8v v = hwv[(size_t)sj * 16 + lane];
#pragma unroll
                for (int k = 0; k < 8; k++) acc[k] = fmaf(wj, bf2f((unsigned short)v[k]), acc[k]);
            }
            for (int j = 0; j < dt - 16; j++) {
                int sj = __shfl(sB, j, 16);
                float wj = __shfl(wB, j, 16);
                ushort8v v = hwv[(size_t)sj * 16 + lane];
#pragma unroll
                for (int k = 0; k < 8; k++) acc[k] = fmaf(wj, bf2f((unsigned short)v[k]), acc[k]);
            }
        } else {
            for (int j = 0; j < d1; j++) {
                int sj = __shfl(sA, j, 16);
                ushort8v v = hwv[(size_t)sj * 16 + lane];
#pragma unroll
                for (int k = 0; k < 8; k++) acc[k] += bf2f((unsigned short)v[k]);
            }
            for (int j = 0; j < dt - 16; j++) {
                int sj = __shfl(sB, j, 16);
                ushort8v v = hwv[(size_t)sj * 16 + lane];
#pragma unroll
                for (int k = 0; k < 8; k++) acc[k] += bf2f((unsigned short)v[k]);
            }
        }
    }
    ushort8v o;
#pragma unroll
    for (int k = 0; k < 8; k++) { acc[k] *= di; o[k] = f2bf(acc[k]); }
    ((ushort8v*)out)[(size_t)g * 16 + lane] = o;

    // BN partials: cols c = lane*8+k; sums at [g16][c], sumsq at [g16][128+c]
    float4 s0 = make_float4(acc[0], acc[1], acc[2], acc[3]);
    float4 s1 = make_float4(acc[4], acc[5], acc[6], acc[7]);
    *(float4*)&part[g16][lane * 8]     = s0;
    *(float4*)&part[g16][lane * 8 + 4] = s1;
    *(float4*)&part[g16][128 + lane * 8] =
        make_float4(s0.x * s0.x, s0.y * s0.y, s0.z * s0.z, s0.w * s0.w);
    *(float4*)&part[g16][128 + lane * 8 + 4] =
        make_float4(s1.x * s1.x, s1.y * s1.y, s1.z * s1.z, s1.w * s1.w);
    __syncthreads();
    int c = threadIdx.x;   // 0..255: 0..127 sums, 128..255 sumsq
    float tot = 0.f;
#pragma unroll
    for (int g2 = 0; g2 < 16; g2++) tot += part[g2][c];
    atomicAdd(&rep[(blockIdx.x & (NREP - 1)) * 256 + c], tot);
}

// ============================================================
// Reduce NREP replicas -> sc/sh; re-zero replicas for next layer.
// ============================================================
__global__ void bn_reduce_finalize_kernel(const float* __restrict__ gamma,
                                          const float* __restrict__ beta,
                                          float* __restrict__ rep,
                                          float* __restrict__ sc_sh) {
    int c = threadIdx.x;
    if (c >= 128) return;
    float s = 0.f, q = 0.f;
#pragma unroll 4
    for (int rr = 0; rr < NREP; rr++) {
        s += rep[rr * 256 + c];
        q += rep[rr * 256 + 128 + c];
        rep[rr * 256 + c] = 0.f;
        rep[rr * 256 + 128 + c] = 0.f;
    }
    float inv_n = 1.0f / (float)N_NODES;
    float mean = s * inv_n;
    float var = q * inv_n - mean * mean;
    float inv = rsqrtf(var + BN_EPS);
    float sc = gamma[c] * inv;
    sc_sh[c] = sc;
    sc_sh[128 + c] = beta[c] - mean * sc;
}

// final layer: bf16 agg -> BN+ReLU -> fp32 d_out
__global__ void bn_apply_kernel(const unsigned short* __restrict__ h,
                                const float* __restrict__ sc_sh,
                                float* __restrict__ out) {
    int i = blockIdx.x * blockDim.x + threadIdx.x;
    int stride = gridDim.x * blockDim.x;
    const int total = N_NODES * 32;
    for (; i < total; i += stride) {
        int cg = i & 31;
        ushort4 u = ((const ushort4*)h)[i];
        float4 sc = ((const float4*)sc_sh)[cg];
        float4 sh = ((const float4*)sc_sh)[32 + cg];
        float4 v;
        v.x = fmaxf(fmaf(bf2f(u.x), sc.x, sh.x), 0.f);
        v.y = fmaxf(fmaf(bf2f(u.y), sc.y, sh.y), 0.f);
        v.z = fmaxf(fmaf(bf2f(u.z), sc.z, sh.z), 0.f);
        v.w = fmaxf(fmaf(bf2f(u.w), sc.w, sh.w), 0.f);
        ((float4*)out)[i] = v;
    }
}

// ============================================================
// Launch
// ============================================================
extern "C" void kernel_launch(void* const* d_in, const int* in_sizes, int n_in,
                              void* d_out, int out_size, void* d_ws, size_t ws_size,
                              hipStream_t stream) {
    const float* x = (const float*)d_in[0];
    const int* ei = (const int*)d_in[1];
    const int* src = ei;
    const int* dst = ei + N_EDGES;
    const float* Wm[3] = {(const float*)d_in[2], (const float*)d_in[6], (const float*)d_in[10]};
    const float* gm[3] = {(const float*)d_in[4], (const float*)d_in[8], (const float*)d_in[12]};
    const float* bm[3] = {(const float*)d_in[5], (const float*)d_in[9], (const float*)d_in[13]};

    char* p = (char*)d_ws;
    auto carve = [&](size_t bytes) { char* r = p; p += (bytes + 255) & ~(size_t)255; return r; };
    unsigned short* hwB    = (unsigned short*)carve((size_t)N_NODES * D * sizeof(unsigned short));
    unsigned short* aggbf  = (unsigned short*)carve((size_t)N_NODES * D * sizeof(unsigned short));
    unsigned short* Wt     = (unsigned short*)carve((size_t)3 * D * D * sizeof(unsigned short));
    float*          dinv   = (float*)carve((N_NODES + 64) * sizeof(float));
    // cnt8 | rep | gcnt contiguous; only rep+gcnt need zeroing (cnt8 is
    // written wholesale by csr_scatter)
    unsigned int*   cnt8   = (unsigned int*)carve((size_t)(N_NODES * 8 + NREP * 256 + NRANGE * NSUB) * sizeof(unsigned int));
    float*          rep    = (float*)(cnt8 + (size_t)N_NODES * 8);
    unsigned int*   gcnt   = cnt8 + (size_t)N_NODES * 8 + NREP * 256;
    unsigned short* csr    = (unsigned short*)carve((size_t)N_NODES * ROWL * sizeof(unsigned short));
    unsigned int*   glist  = (unsigned int*)carve((size_t)NRANGE * NSUB * SEG_CAP * sizeof(unsigned int));
    float*          sc_sh  = (float*)carve(256 * sizeof(float));

    // ---- prep: zero BN replicas + segment heads, transpose weights ----
    hipMemsetAsync(rep, 0, (size_t)(NREP * 256 + NRANGE * NSUB) * sizeof(unsigned int), stream);
    prep_weights_kernel<<<3, 256, 0, stream>>>(Wm[0], Wm[1], Wm[2], Wt);

    // ---- fused: phase-A binning || layer-0 GEMM ----
    fused_bin_gemm0_kernel<<<BIN_BLOCKS + GEMM0_BLOCKS, 256, 0, stream>>>(
        src, dst, gcnt, glist, x, Wt, hwB);

    // ---- phase B: LDS scatter -> csr + cnt8 (atomic-free in global) ----
    csr_scatter_kernel<<<NRANGE, 256, 0, stream>>>(glist, gcnt, cnt8, csr);
    compute_dinv_kernel<<<(N_NODES + 255) / 256, 256, 0, stream>>>(cnt8, dinv);

    // ---- layer 0: weighted gather (hw unscaled) ----
    gather_agg_stats_kernel<<<N_NODES / 16, 256, 0, stream>>>(hwB, csr, cnt8, dinv, aggbf, rep, 1);
    bn_reduce_finalize_kernel<<<1, 128, 0, stream>>>(gm[0], bm[0], rep, sc_sh);

    // ---- layers 1,2: BN fused into GEMM, dinv pre-scaled hw ----
    for (int l = 1; l < 3; l++) {
        gemm_mfma_kernel<<<GEMM_BLOCKS, 128, 0, stream>>>(aggbf, Wt + (size_t)l * D * D, sc_sh, dinv, hwB);
        gather_agg_stats_kernel<<<N_NODES / 16, 256, 0, stream>>>(hwB, csr, cnt8, dinv, aggbf, rep, 0);
        bn_reduce_finalize_kernel<<<1, 128, 0, stream>>>(gm[l], bm[l], rep, sc_sh);
    }
    bn_apply_kernel<<<2048, 256, 0, stream>>>(aggbf, sc_sh, (float*)d_out);
}

// Round 7
// 440.306 us; speedup vs baseline: 1.1896x; 1.0341x over previous
//
#include <hip/hip_runtime.h>
#include <math.h>

#define N_NODES 50000
#define N_EDGES 1600000
#define D 128
#define BN_EPS 1e-5f

#define NSLICE 8
#define SLICE_NODES 6250        // divides 50000 exactly; src-bucket granularity for gather L2 locality
#define SUBB 24                 // slots per (node, src-slice); Poisson(4), P(>=24)~8e-12
#define ROWL (NSLICE * SUBB)    // 192 u16 per node = 384 B
#define NREP 64                 // BN partial-sum replicas

// R16: LDS-scatter CSR build (WIN: fill wall eliminated). R2/R3/R5 triangulated
// that the old fill wall was the 1.6M returning L2 atomics + dependent 2B
// scatters; phase A bins edges by dst-range (bulk-reserved appends), phase B
// scatters ENTIRELY in LDS and writes csr/cnt8 coalesced.
#define NRANGE 500
#define RANGE_NODES 100         // 500 * 100 = 50000 exact
#define NSUB 8                  // sub-heads per range (blockIdx&7) to cut reserve contention
#define SEG_CAP 512             // per-(range,sub) list segment; mean 400, +5.6 sigma
#define BIN_TILE 2048
#define BIN_CAP2 16             // per-tile per-range LDS bucket; mean 4.1, P(>16)~5e-6
#define BIN_BLOCKS ((N_EDGES + BIN_TILE - 1) / BIN_TILE)  // 782
#define GEMM0_BLOCKS ((N_NODES + 63) / 64)   // 782 (64 rows, 4 waves) — fused with phase A
#define GEMM_BLOCKS ((N_NODES + 31) / 32)    // 1563 (32 rows, 2 waves)

typedef __attribute__((ext_vector_type(8))) short short8;
typedef __attribute__((ext_vector_type(8))) unsigned short ushort8v;
typedef __attribute__((ext_vector_type(4))) float f32x4;

// bf16 helpers (manual, RNE)
__device__ __forceinline__ unsigned short f2bf(float f) {
    unsigned u = __float_as_uint(f);
    u += 0x7FFFu + ((u >> 16) & 1u);
    return (unsigned short)(u >> 16);
}
__device__ __forceinline__ float bf2f(unsigned short u) {
    return __uint_as_float(((unsigned)u) << 16);
}

// ============================================================
// GEMM body (16 rows per wave): out[rowbase..rowbase+15] = act(A) @ W
//   apply_bn=0: A = Af32 (fp32 -> bf16), act = identity
//   apply_bn=1: A = Abf (bf16), act = relu(a*sc+sh)
// Global-direct fragments (m89-verified layouts); optional dinv row-scale.
// ============================================================
__device__ __forceinline__ void gemm_body(int rowbase, const float* __restrict__ Af32,
                                          const unsigned short* __restrict__ Abf,
                                          const unsigned short* __restrict__ Wt,
                                          const float* __restrict__ sc_sh,
                                          const float* __restrict__ dinv,
                                          int apply_bn,
                                          unsigned short* __restrict__ outbf,
                                          unsigned short* Cs) {   // per-wave 16x136 at Cs[w*2176]
    int tid = threadIdx.x;
    int w = tid >> 6;
    int lane = tid & 63;
    int r = lane & 15, quad = lane >> 4;
    rowbase += w * 16;
    int arow = rowbase + r;
    int arowc = (arow < N_NODES) ? arow : 0;

    f32x4 acc[8] = {};
#pragma unroll
    for (int kc = 0; kc < 128; kc += 32) {
        int ko = kc + quad * 8;
        short8 a;
        if (apply_bn) {
            short8 araw = *(const short8*)&Abf[(size_t)arowc * D + ko];
            const float* sc = &sc_sh[ko];
            const float* sh = &sc_sh[128 + ko];
#pragma unroll
            for (int j = 0; j < 8; j++) {
                float v = bf2f((unsigned short)araw[j]);
                v = fmaxf(fmaf(v, sc[j], sh[j]), 0.f);
                a[j] = (short)f2bf(v);
            }
        } else {
            float4 v0 = *(const float4*)&Af32[(size_t)arowc * D + ko];
            float4 v1 = *(const float4*)&Af32[(size_t)arowc * D + ko + 4];
            a[0] = (short)f2bf(v0.x); a[1] = (short)f2bf(v0.y);
            a[2] = (short)f2bf(v0.z); a[3] = (short)f2bf(v0.w);
            a[4] = (short)f2bf(v1.x); a[5] = (short)f2bf(v1.y);
            a[6] = (short)f2bf(v1.z); a[7] = (short)f2bf(v1.w);
        }
#pragma unroll
        for (int ct = 0; ct < 8; ct++) {
            short8 b = *(const short8*)&Wt[(size_t)(ct * 16 + r) * D + ko];
            acc[ct] = __builtin_amdgcn_mfma_f32_16x16x32_bf16(a, b, acc[ct], 0, 0, 0);
        }
    }
    float dv[4] = {1.f, 1.f, 1.f, 1.f};
    if (dinv) {
        float4 d4 = *(const float4*)&dinv[rowbase + quad * 4];  // padded past N
        dv[0] = d4.x; dv[1] = d4.y; dv[2] = d4.z; dv[3] = d4.w;
    }
    // epilogue: wave-private LDS staging (no cross-wave deps -> no barrier)
#pragma unroll
    for (int ct = 0; ct < 8; ct++)
#pragma unroll
        for (int i = 0; i < 4; i++)
            Cs[w * 2176 + (quad * 4 + i) * 136 + ct * 16 + r] = f2bf(acc[ct][i] * dv[i]);

    int r2 = lane >> 2;   // 0..15
    int seg = lane & 3;   // 0..3, 32 cols each
    int orow = rowbase + r2;
    if (orow < N_NODES) {
#pragma unroll
        for (int jj = 0; jj < 4; jj++) {
            *(ushort8v*)&outbf[(size_t)orow * D + seg * 32 + jj * 8] =
                *(const ushort8v*)&Cs[w * 2176 + r2 * 136 + seg * 32 + jj * 8];
        }
    }
}

// ============================================================
// Fused: phase-A edge binning (blocks [0,782)) || layer-0 GEMM ([782,1564)).
// ============================================================
__global__ __launch_bounds__(256) void fused_bin_gemm0_kernel(const int* __restrict__ src,
                                                              const int* __restrict__ dst,
                                                              unsigned int* __restrict__ gcnt,
                                                              unsigned int* __restrict__ glist,
                                                              const float* __restrict__ x,
                                                              const unsigned short* __restrict__ Wt0,
                                                              unsigned short* __restrict__ hwB) {
    __shared__ __align__(16) char smem[34000];   // union: binning 34000B | gemm0 Cs 17408B
    if (blockIdx.x < BIN_BLOCKS) {
        unsigned* lcnt = (unsigned*)smem;                 // [500]
        unsigned* lbuf = (unsigned*)(smem + 2000);        // [500 * 16]
        int tid = threadIdx.x;
        int sub = blockIdx.x & (NSUB - 1);
        for (int i = tid; i < NRANGE; i += 256) lcnt[i] = 0;
        __syncthreads();
        int e0 = blockIdx.x * BIN_TILE;
#pragma unroll
        for (int j = 0; j < BIN_TILE / 256; j++) {
            int e = e0 + j * 256 + tid;
            if (e < N_EDGES) {
                int d = dst[e];
                int s = src[e];
                int rg = d / RANGE_NODES;
                unsigned val = ((unsigned)(d - rg * RANGE_NODES) << 16) | (unsigned)s;
                unsigned pos = atomicAdd(&lcnt[rg], 1u);
                if (pos < BIN_CAP2) {
                    lbuf[rg * BIN_CAP2 + pos] = val;
                } else {   // rare bucket overflow (~10 events/run): direct bounded append
                    unsigned gp = atomicAdd(&gcnt[rg * NSUB + sub], 1u);
                    if (gp < SEG_CAP) glist[(size_t)(rg * NSUB + sub) * SEG_CAP + gp] = val;
                }
            }
        }
        __syncthreads();
        // bulk-reserve + flush: thread t owns ranges t, t+256
        for (int rg = tid; rg < NRANGE; rg += 256) {
            unsigned c = lcnt[rg];
            if (c > BIN_CAP2) c = BIN_CAP2;
            if (c == 0) continue;
            unsigned b = atomicAdd(&gcnt[rg * NSUB + sub], c);
            unsigned base = (unsigned)(rg * NSUB + sub) * SEG_CAP;
            for (unsigned j = 0; j < c; j++) {
                unsigned idx = b + j;
                if (idx < SEG_CAP) glist[base + idx] = lbuf[rg * BIN_CAP2 + j];
            }
        }
    } else {
        gemm_body((blockIdx.x - BIN_BLOCKS) * 64, x, nullptr, Wt0, nullptr, nullptr, 0, hwB,
                  (unsigned short*)smem);
    }
}

// ============================================================
// Phase B: per-range LDS scatter (1.6M LDS atomics, zero global atomics);
// csr + cnt8 written out fully coalesced, exactly once.
// ============================================================
__global__ __launch_bounds__(256) void csr_scatter_kernel(const unsigned int* __restrict__ glist,
                                                          const unsigned int* __restrict__ gcnt,
                                                          unsigned int* __restrict__ cnt8,
                                                          unsigned short* __restrict__ csr) {
    __shared__ __align__(16) unsigned int cnt[RANGE_NODES * 8];        // 3200 B
    __shared__ __align__(16) unsigned short slab[RANGE_NODES * ROWL];  // 38400 B
    int tid = threadIdx.x;
    int rg = blockIdx.x;
    for (int i = tid; i < RANGE_NODES * 8; i += 256) cnt[i] = 0;
    __syncthreads();
#pragma unroll 1
    for (int sub = 0; sub < NSUB; sub++) {
        unsigned c = gcnt[rg * NSUB + sub];
        if (c > SEG_CAP) c = SEG_CAP;
        const unsigned int* seg = glist + (size_t)(rg * NSUB + sub) * SEG_CAP;
        for (unsigned j = tid; j < c; j += 256) {
            unsigned v = seg[j];
            int dl = (int)(v >> 16);
            int s = (int)(v & 0xFFFFu);
            int t = s / SLICE_NODES;
            unsigned pos = atomicAdd(&cnt[dl * 8 + t], 1u);   // LDS atomic
            if (pos < SUBB) slab[dl * ROWL + t * SUBB + pos] = (unsigned short)s;
        }
    }
    __syncthreads();
    // coalesced write-out: 2400 x ushort8 csr + 200 x uint4 counters
    unsigned short* crow = csr + (size_t)rg * RANGE_NODES * ROWL;
    const ushort8v* sl = (const ushort8v*)slab;
    for (int i = tid; i < RANGE_NODES * ROWL / 8; i += 256)
        ((ushort8v*)crow)[i] = sl[i];
    unsigned int* gout = cnt8 + (size_t)rg * RANGE_NODES * 8;
    const uint4* cl = (const uint4*)cnt;
    for (int i = tid; i < RANGE_NODES * 8 / 4; i += 256)
        ((uint4*)gout)[i] = cl[i];
}

// standalone GEMM for layers 1,2 (BN fused, dinv pre-scale); 128 thr = 2 waves,
// 32 rows/block -> 1563 blocks (782-block config wasted a 14/256 dispatch tail)
__global__ __launch_bounds__(128) void gemm_mfma_kernel(const unsigned short* __restrict__ Abf,
                                                        const unsigned short* __restrict__ Wt,
                                                        const float* __restrict__ sc_sh,
                                                        const float* __restrict__ dinv,
                                                        unsigned short* __restrict__ outbf) {
    __shared__ unsigned short Cs[2 * 2176];
    gemm_body(blockIdx.x * 32, nullptr, Abf, Wt, sc_sh, dinv, 1, outbf, Cs);
}

__global__ void compute_dinv_kernel(const unsigned int* __restrict__ cnt8, float* __restrict__ dinv) {
    int n = blockIdx.x * blockDim.x + threadIdx.x;
    if (n < N_NODES) {
        const uint4* c = (const uint4*)&cnt8[n << 3];
        uint4 a = c[0], b = c[1];
        unsigned deg = a.x + a.y + a.z + a.w + b.x + b.y + b.z + b.w;
        dinv[n] = rsqrtf((float)deg + 2.0f);   // improved=True: self-loop weight 2
    }
}

// ============================================================
// Per-layer weight prep: Wt[n][k] = bf16(W[k][n]), 3 layers, 3 blocks.
// ============================================================
__global__ void prep_weights_kernel(const float* __restrict__ W0, const float* __restrict__ W1,
                                    const float* __restrict__ W2, unsigned short* __restrict__ Wt) {
    const float* W = (blockIdx.x == 0) ? W0 : (blockIdx.x == 1) ? W1 : W2;
    unsigned short* o = Wt + (size_t)blockIdx.x * D * D;
    int t = threadIdx.x;
    int n = t & 127, half = t >> 7;
    __attribute__((aligned(16))) unsigned short buf[64];
    for (int j = 0; j < 64; j++) {
        int k = half * 64 + j;
        buf[j] = f2bf(W[(size_t)k * D + n]);
    }
    for (int j = 0; j < 64; j += 8)
        *(ushort8v*)&o[(size_t)n * D + half * 64 + j] = *(const ushort8v*)&buf[j];
}

// ============================================================
// Fused gather + BN-stats — 4 nodes/wave in 16-lane groups, lane owns 8 cols.
// R17: kill the per-phase dependent-load chain (gather was 66us at VALUBusy
// 35%, neither BW- nor VALU-bound => latency on cnt8->row->dinv chains):
//  (a) 8 cnt8 loads hoisted into 2 uint4 vector loads (unrolled-t selects),
//  (b) row ids + dinv weights software-pipelined one phase ahead (named
//      double-buffer regs, no runtime-indexed arrays),
//  (c) part[] padded [16][260] to kill 400K 4-way LDS bank conflicts.
// Node batching (4 nodes/wave, 16-lane groups) unchanged (r7/r8 lesson).
//   weighted=1 (layer 0, hw raw):   agg = di*( sum dinv[s]*hw[s] + 2*di*hw[g] )
//   weighted=0 (layers 1+, pre-scaled): agg = di*( sum hw'[s] + 2*hw'[g] )
// ============================================================
#define CNT_AT(t) ((t)==0?ca.x:(t)==1?ca.y:(t)==2?ca.z:(t)==3?ca.w:(t)==4?cb.x:(t)==5?cb.y:(t)==6?cb.z:cb.w)

__global__ __launch_bounds__(256) void gather_agg_stats_kernel(const unsigned short* __restrict__ hw,
                                                               const unsigned short* __restrict__ csr,
                                                               const unsigned int* __restrict__ cnt8,
                                                               const float* __restrict__ dinv,
                                                               unsigned short* __restrict__ out,
                                                               float* __restrict__ rep,
                                                               int weighted) {
    __shared__ float part[16][260];     // 260-stride: de-conflicts float4 stats writes
    int g16 = threadIdx.x >> 4, lane = threadIdx.x & 15;
    int g = blockIdx.x * 16 + g16;             // 3125 * 16 = 50000 exact
    const ushort8v* hwv = (const ushort8v*)hw; // row = 16 x ushort8
    float di = dinv[g];
    ushort8v sv = hwv[(size_t)g * 16 + lane];
    // hoisted counts: 2 vector loads replace 8 serial dependent scalar loads
    uint4 ca = *(const uint4*)&cnt8[g << 3];
    uint4 cb = *(const uint4*)&cnt8[(g << 3) + 4];
    float w0 = weighted ? (2.f * di) : 2.f;
    float acc[8];
#pragma unroll
    for (int k = 0; k < 8; k++) acc[k] = w0 * bf2f((unsigned short)sv[k]);
    const unsigned short* row = csr + (size_t)g * ROWL;

    // pipeline prologue: phase-0 ids/weights
    int sAc = 0, sBc = 0; float wAc = 0.f, wBc = 0.f;
    {
        int dt0 = (int)CNT_AT(0); if (dt0 > SUBB) dt0 = SUBB;
        if (lane < dt0) { sAc = (int)row[lane]; if (weighted) wAc = dinv[sAc]; }
        if (lane + 16 < dt0) { sBc = (int)row[16 + lane]; if (weighted) wBc = dinv[sBc]; }
    }
#pragma unroll
    for (int t = 0; t < NSLICE; t++) {
        int dt = (int)CNT_AT(t); if (dt > SUBB) dt = SUBB;
        // issue phase-(t+1) loads NOW; they complete under phase-t compute
        int sAn = 0, sBn = 0; float wAn = 0.f, wBn = 0.f;
        if (t < NSLICE - 1) {
            int dtn = (int)CNT_AT(t + 1); if (dtn > SUBB) dtn = SUBB;
            if (lane < dtn) { sAn = (int)row[(t + 1) * SUBB + lane]; if (weighted) wAn = dinv[sAn]; }
            if (lane + 16 < dtn) { sBn = (int)row[(t + 1) * SUBB + 16 + lane]; if (weighted) wBn = dinv[sBn]; }
        }
        int d1 = dt < 16 ? dt : 16;
        if (weighted) {
            for (int j = 0; j < d1; j++) {
                int sj = __shfl(sAc, j, 16);
                float wj = __shfl(wAc, j, 16);
                ushort8v v = hwv[(size_t)sj * 16 + lane];
#pragma unroll
                for (int k = 0; k < 8; k++) acc[k] = fmaf(wj, bf2f((unsigned short)v[k]), acc[k]);
            }
            for (int j = 0; j < dt - 16; j++) {
                int sj = __shfl(sBc, j, 16);
                float wj = __shfl(wBc, j, 16);
                ushort8v v = hwv[(size_t)sj * 16 + lane];
#pragma unroll
                for (int k = 0; k < 8; k++) acc[k] = fmaf(wj, bf2f((unsigned short)v[k]), acc[k]);
            }
        } else {
            for (int j = 0; j < d1; j++) {
                int sj = __shfl(sAc, j, 16);
                ushort8v v = hwv[(size_t)sj * 16 + lane];
#pragma unroll
                for (int k = 0; k < 8; k++) acc[k] += bf2f((unsigned short)v[k]);
            }
            for (int j = 0; j < dt - 16; j++) {
                int sj = __shfl(sBc, j, 16);
                ushort8v v = hwv[(size_t)sj * 16 + lane];
#pragma unroll
                for (int k = 0; k < 8; k++) acc[k] += bf2f((unsigned short)v[k]);
            }
        }
        sAc = sAn; sBc = sBn; wAc = wAn; wBc = wBn;
    }
    ushort8v o;
#pragma unroll
    for (int k = 0; k < 8; k++) { acc[k] *= di; o[k] = f2bf(acc[k]); }
    ((ushort8v*)out)[(size_t)g * 16 + lane] = o;

    // BN partials: cols c = lane*8+k; sums at [g16][c], sumsq at [g16][128+c]
    float4 s0 = make_float4(acc[0], acc[1], acc[2], acc[3]);
    float4 s1 = make_float4(acc[4], acc[5], acc[6], acc[7]);
    *(float4*)&part[g16][lane * 8]     = s0;
    *(float4*)&part[g16][lane * 8 + 4] = s1;
    *(float4*)&part[g16][128 + lane * 8] =
        make_float4(s0.x * s0.x, s0.y * s0.y, s0.z * s0.z, s0.w * s0.w);
    *(float4*)&part[g16][128 + lane * 8 + 4] =
        make_float4(s1.x * s1.x, s1.y * s1.y, s1.z * s1.z, s1.w * s1.w);
    __syncthreads();
    int c = threadIdx.x;   // 0..255: 0..127 sums, 128..255 sumsq
    float tot = 0.f;
#pragma unroll
    for (int g2 = 0; g2 < 16; g2++) tot += part[g2][c];
    atomicAdd(&rep[(blockIdx.x & (NREP - 1)) * 256 + c], tot);
}

// ============================================================
// Reduce NREP replicas -> sc/sh; re-zero replicas for next layer.
// ============================================================
__global__ void bn_reduce_finalize_kernel(const float* __restrict__ gamma,
                                          const float* __restrict__ beta,
                                          float* __restrict__ rep,
                                          float* __restrict__ sc_sh) {
    int c = threadIdx.x;
    if (c >= 128) return;
    float s = 0.f, q = 0.f;
#pragma unroll 4
    for (int rr = 0; rr < NREP; rr++) {
        s += rep[rr * 256 + c];
        q += rep[rr * 256 + 128 + c];
        rep[rr * 256 + c] = 0.f;
        rep[rr * 256 + 128 + c] = 0.f;
    }
    float inv_n = 1.0f / (float)N_NODES;
    float mean = s * inv_n;
    float var = q * inv_n - mean * mean;
    float inv = rsqrtf(var + BN_EPS);
    float sc = gamma[c] * inv;
    sc_sh[c] = sc;
    sc_sh[128 + c] = beta[c] - mean * sc;
}

// final layer: bf16 agg -> BN+ReLU -> fp32 d_out
__global__ void bn_apply_kernel(const unsigned short* __restrict__ h,
                                const float* __restrict__ sc_sh,
                                float* __restrict__ out) {
    int i = blockIdx.x * blockDim.x + threadIdx.x;
    int stride = gridDim.x * blockDim.x;
    const int total = N_NODES * 32;
    for (; i < total; i += stride) {
        int cg = i & 31;
        ushort4 u = ((const ushort4*)h)[i];
        float4 sc = ((const float4*)sc_sh)[cg];
        float4 sh = ((const float4*)sc_sh)[32 + cg];
        float4 v;
        v.x = fmaxf(fmaf(bf2f(u.x), sc.x, sh.x), 0.f);
        v.y = fmaxf(fmaf(bf2f(u.y), sc.y, sh.y), 0.f);
        v.z = fmaxf(fmaf(bf2f(u.z), sc.z, sh.z), 0.f);
        v.w = fmaxf(fmaf(bf2f(u.w), sc.w, sh.w), 0.f);
        ((float4*)out)[i] = v;
    }
}

// ============================================================
// Launch
// ============================================================
extern "C" void kernel_launch(void* const* d_in, const int* in_sizes, int n_in,
                              void* d_out, int out_size, void* d_ws, size_t ws_size,
                              hipStream_t stream) {
    const float* x = (const float*)d_in[0];
    const int* ei = (const int*)d_in[1];
    const int* src = ei;
    const int* dst = ei + N_EDGES;
    const float* Wm[3] = {(const float*)d_in[2], (const float*)d_in[6], (const float*)d_in[10]};
    const float* gm[3] = {(const float*)d_in[4], (const float*)d_in[8], (const float*)d_in[12]};
    const float* bm[3] = {(const float*)d_in[5], (const float*)d_in[9], (const float*)d_in[13]};

    char* p = (char*)d_ws;
    auto carve = [&](size_t bytes) { char* r = p; p += (bytes + 255) & ~(size_t)255; return r; };
    unsigned short* hwB    = (unsigned short*)carve((size_t)N_NODES * D * sizeof(unsigned short));
    unsigned short* aggbf  = (unsigned short*)carve((size_t)N_NODES * D * sizeof(unsigned short));
    unsigned short* Wt     = (unsigned short*)carve((size_t)3 * D * D * sizeof(unsigned short));
    float*          dinv   = (float*)carve((N_NODES + 64) * sizeof(float));
    // cnt8 | rep | gcnt contiguous; only rep+gcnt need zeroing (cnt8 is
    // written wholesale by csr_scatter)
    unsigned int*   cnt8   = (unsigned int*)carve((size_t)(N_NODES * 8 + NREP * 256 + NRANGE * NSUB) * sizeof(unsigned int));
    float*          rep    = (float*)(cnt8 + (size_t)N_NODES * 8);
    unsigned int*   gcnt   = cnt8 + (size_t)N_NODES * 8 + NREP * 256;
    unsigned short* csr    = (unsigned short*)carve((size_t)N_NODES * ROWL * sizeof(unsigned short));
    unsigned int*   glist  = (unsigned int*)carve((size_t)NRANGE * NSUB * SEG_CAP * sizeof(unsigned int));
    float*          sc_sh  = (float*)carve(256 * sizeof(float));

    // ---- prep: zero BN replicas + segment heads, transpose weights ----
    hipMemsetAsync(rep, 0, (size_t)(NREP * 256 + NRANGE * NSUB) * sizeof(unsigned int), stream);
    prep_weights_kernel<<<3, 256, 0, stream>>>(Wm[0], Wm[1], Wm[2], Wt);

    // ---- fused: phase-A binning || layer-0 GEMM ----
    fused_bin_gemm0_kernel<<<BIN_BLOCKS + GEMM0_BLOCKS, 256, 0, stream>>>(
        src, dst, gcnt, glist, x, Wt, hwB);

    // ---- phase B: LDS scatter -> csr + cnt8 (atomic-free in global) ----
    csr_scatter_kernel<<<NRANGE, 256, 0, stream>>>(glist, gcnt, cnt8, csr);
    compute_dinv_kernel<<<(N_NODES + 255) / 256, 256, 0, stream>>>(cnt8, dinv);

    // ---- layer 0: weighted gather (hw unscaled) ----
    gather_agg_stats_kernel<<<N_NODES / 16, 256, 0, stream>>>(hwB, csr, cnt8, dinv, aggbf, rep, 1);
    bn_reduce_finalize_kernel<<<1, 128, 0, stream>>>(gm[0], bm[0], rep, sc_sh);

    // ---- layers 1,2: BN fused into GEMM, dinv pre-scaled hw ----
    for (int l = 1; l < 3; l++) {
        gemm_mfma_kernel<<<GEMM_BLOCKS, 128, 0, stream>>>(aggbf, Wt + (size_t)l * D * D, sc_sh, dinv, hwB);
        gather_agg_stats_kernel<<<N_NODES / 16, 256, 0, stream>>>(hwB, csr, cnt8, dinv, aggbf, rep, 0);
        bn_reduce_finalize_kernel<<<1, 128, 0, stream>>>(gm[l], bm[l], rep, sc_sh);
    }
    bn_apply_kernel<<<2048, 256, 0, stream>>>(aggbf, sc_sh, (float*)d_out);
}